// Round 7
// baseline (105.807 us; speedup 1.0000x reference)
//
#include <hip/hip_runtime.h>
#include <math.h>

typedef unsigned int u32;
typedef unsigned short u16;
typedef __attribute__((ext_vector_type(2))) u32 u32x2;
typedef __attribute__((ext_vector_type(4))) u32 u32x4;
typedef __attribute__((ext_vector_type(8))) short bf16x8;
typedef __attribute__((ext_vector_type(4))) float f32x4;

#define FDIM 76
#define NCELL 5776
#define NA 3
#define NCH 85
#define NCLS 80
#define KLAB 40
#define NB 16
#define CIN 256
#define TILES_PER_B 91
#define NBLK (NB * TILES_PER_B)   // 1456
#define CS_LD 68                  // Csb row stride in u16

// fast-math helpers (epilogue; tolerance is 2% of 2.4e5, hw exp/log err ~1e-5 rel)
__device__ __forceinline__ float sigmf_(float x) { return 1.0f / (1.0f + __expf(-x)); }
__device__ __forceinline__ float bce_fullf(float p, float t) {
    return -(t * fmaxf(__logf(p), -100.0f) + (1.0f - t) * fmaxf(__logf(1.0f - p), -100.0f));
}
__device__ __forceinline__ float bce1f(float p) { return -fmaxf(__logf(p), -100.0f); }
__device__ __forceinline__ float bce0f(float p) { return -fmaxf(__logf(1.0f - p), -100.0f); }

__device__ __forceinline__ u16 bf16rne(float f) {
    u32 u = __float_as_uint(f);
    u32 r = u + 0x7fffu + ((u >> 16) & 1u);
    return (u16)(r >> 16);
}
__device__ __forceinline__ float bf16f(u16 v) { return __uint_as_float(((u32)v) << 16); }

// ---- W fp32 -> bf16, padded to [256][256] (row 255 zero) ----
__global__ __launch_bounds__(256) void yolo_wconv(const float* __restrict__ W,
                                                  u16* __restrict__ Wbf) {
    int idx = blockIdx.x * 256 + threadIdx.x;
    int row = idx >> 8, col = idx & 255;
    float v = (row < NA * NCH) ? W[row * CIN + col] : 0.0f;
    Wbf[idx] = bf16rne(v);
}

// ---- label prep (verified exact) ----
__global__ __launch_bounds__(64) void yolo_lab(const float* __restrict__ labels,
                                               float* __restrict__ lrec) {
    int idx = blockIdx.x * 64 + threadIdx.x;
    if (idx >= NB * KLAB) return;
    const float* l = labels + idx * 5;
    float cls = l[0], x = l[1], y = l[2], ww = l[3], hh = l[4];
    bool valid = (cls + x + y + ww + hh) > 0.0f;
    float tx = x * FDIM, ty = y * FDIM, tw = ww * FDIM, th = hh * FDIM;
    int ti = (int)tx, tj = (int)ty;
    float area_a = (tw - tx) * (th - ty);
    const float aw[9] = {1.25f, 2.0f, 4.125f, 3.75f, 7.75f, 7.375f, 14.5f, 19.5f, 46.625f};
    const float ah[9] = {1.625f, 3.75f, 2.875f, 7.625f, 5.625f, 14.875f, 11.25f, 24.75f, 40.75f};
    float best = -1e30f;
    int bi = 0;
    for (int n = 0; n < 9; n++) {
        float bw = fminf(tw, aw[n]), bh = fminf(th, ah[n]);
        float ai = ((tx < bw) && (ty < bh)) ? (bw - tx) * (bh - ty) : 0.0f;
        float iou = valid ? ai / (area_a + aw[n] * ah[n] - ai) : -1.0f;
        if (iou > best) { best = iou; bi = n; }
    }
    int bn = bi % 3;
    bool assign = valid && (bi < 3);
    float* r = lrec + idx * 16;
    r[0] = tx - 0.5f * tw; r[1] = ty - 0.5f * th;
    r[2] = tx + 0.5f * tw; r[3] = ty + 0.5f * th;
    r[4] = tw * th; r[5] = valid ? 1.0f : 0.0f;
    r[6] = tx - (float)ti; r[7] = ty - (float)tj;
    r[8] = logf(tw / aw[bn] + 1e-16f); r[9] = logf(th / ah[bn] + 1e-16f);
    r[10] = cls; r[11] = sqrtf(2.0f - tw * th / (float)(FDIM * FDIM));
    r[12] = assign ? 1.0f : 0.0f; r[13] = (float)bn; r[14] = (float)ti; r[15] = (float)tj;
}

// ---- fused GEMM+loss: 8 waves, 2x4 frags/wave (32 acc), no-spill budget ----
__global__ __launch_bounds__(512, 4) void yolo_mfma(const float* __restrict__ xin,
                                                    const u16* __restrict__ Wbf,
                                                    const float* __restrict__ bias,
                                                    const float* __restrict__ lrec,
                                                    float* __restrict__ partials) {
    __shared__ char smem[34816];        // GEMM: Xs buf0 [0,8K) buf1 [8K,16K); epi: Csb [256][68] bf16
    __shared__ float Lb[KLAB * 16];
    __shared__ float red[8][8];

    u16* Csb = (u16*)smem;

    const int blk = blockIdx.x;
    const int b = blk / TILES_PER_B;
    const int tile = blk - b * TILES_PER_B;
    const int cell0 = tile * 64;
    const int t = threadIdx.x;
    const int lane = t & 63;
    const int wid = t >> 6;             // 0..7
    const int g = lane >> 4;
    const int l15 = lane & 15;

    for (int i = t; i < KLAB * 16; i += 512) Lb[i] = lrec[b * KLAB * 16 + i];

    f32x4 acc[2][4];
#pragma unroll
    for (int mi = 0; mi < 2; mi++)
#pragma unroll
        for (int ni = 0; ni < 4; ni++) acc[mi][ni] = (f32x4){0.f, 0.f, 0.f, 0.f};

    const float* xbase = xin + (size_t)b * CIN * NCELL;
    const u16* wrow = Wbf + (wid * 32 + l15) * CIN;   // wave owns channels wid*32..wid*32+31

#pragma unroll
    for (int kc = 0; kc < 4; kc++) {
        u16* Xs = (u16*)(smem + ((kc & 1) ? 8192 : 0));
        // --- prefetch s=0 W fragments (8 VGPR) ---
        bf16x8 af0[2];
#pragma unroll
        for (int mi = 0; mi < 2; mi++)
            af0[mi] = *(const bf16x8*)(wrow + mi * 16 * CIN + kc * 64 + g * 8);
        // --- issue X loads (8 dword/thread, coalesced) ---
        float xv[8];
#pragma unroll
        for (int ii = 0; ii < 2; ii++) {
            const int u = t + ii * 512;           // 0..1023: (kq 0..15, cell 0..63)
            const int kq = u >> 6, cell = u & 63;
            const int cg0 = cell0 + cell;
            const int cg = cg0 < NCELL ? cg0 : NCELL - 1;
            const float* xp = xbase + (size_t)(kc * 64 + kq * 4) * NCELL + cg;
            xv[ii * 4 + 0] = xp[0];
            xv[ii * 4 + 1] = xp[NCELL];
            xv[ii * 4 + 2] = xp[2 * NCELL];
            xv[ii * 4 + 3] = xp[3 * NCELL];
        }
        // --- convert + LDS write (waits on X loads; W frags still in flight) ---
#pragma unroll
        for (int ii = 0; ii < 2; ii++) {
            const int u = t + ii * 512;
            const int kq = u >> 6, cell = u & 63;
            u32x2 pv;
            pv.x = (u32)bf16rne(xv[ii * 4 + 0]) | ((u32)bf16rne(xv[ii * 4 + 1]) << 16);
            pv.y = (u32)bf16rne(xv[ii * 4 + 2]) | ((u32)bf16rne(xv[ii * 4 + 3]) << 16);
            const int byte = (cell * 128 + kq * 8) ^ ((cell & 7) << 4);
            *(u32x2*)((char*)Xs + byte) = pv;
        }
        __syncthreads();                 // single barrier per chunk (dbuf makes it legal)
        // --- s = 0: LDS fragment reads, issue s=1 W prefetch, MFMA ---
        bf16x8 bfr[4];
#pragma unroll
        for (int ni = 0; ni < 4; ni++) {
            const int cell = ni * 16 + l15;
            const int byte = (cell * 128 + g * 16) ^ ((cell & 7) << 4);
            bfr[ni] = *(const bf16x8*)((char*)Xs + byte);
        }
        bf16x8 af1[2];
#pragma unroll
        for (int mi = 0; mi < 2; mi++)
            af1[mi] = *(const bf16x8*)(wrow + mi * 16 * CIN + kc * 64 + 32 + g * 8);
#pragma unroll
        for (int mi = 0; mi < 2; mi++)
#pragma unroll
            for (int ni = 0; ni < 4; ni++)
                acc[mi][ni] = __builtin_amdgcn_mfma_f32_16x16x32_bf16(
                    af0[mi], bfr[ni], acc[mi][ni], 0, 0, 0);
        // --- s = 1 ---
#pragma unroll
        for (int ni = 0; ni < 4; ni++) {
            const int cell = ni * 16 + l15;
            const int byte = (cell * 128 + 64 + g * 16) ^ ((cell & 7) << 4);
            bfr[ni] = *(const bf16x8*)((char*)Xs + byte);
        }
#pragma unroll
        for (int mi = 0; mi < 2; mi++)
#pragma unroll
            for (int ni = 0; ni < 4; ni++)
                acc[mi][ni] = __builtin_amdgcn_mfma_f32_16x16x32_bf16(
                    af1[mi], bfr[ni], acc[mi][ni], 0, 0, 0);
    }

    __syncthreads();    // all waves done reading Xs before Csb overwrites the region

    // bias for this thread's 8 output channels
    float bv[8];
#pragma unroll
    for (int mi = 0; mi < 2; mi++)
#pragma unroll
        for (int reg = 0; reg < 4; reg++) {
            const int ch = wid * 32 + mi * 16 + g * 4 + reg;
            bv[mi * 4 + reg] = (ch < NA * NCH) ? bias[ch] : 0.0f;
        }
    // C (+bias) -> LDS bf16 [256][CS_LD]
#pragma unroll
    for (int mi = 0; mi < 2; mi++)
#pragma unroll
        for (int ni = 0; ni < 4; ni++)
#pragma unroll
            for (int reg = 0; reg < 4; reg++) {
                const int ch = wid * 32 + mi * 16 + g * 4 + reg;
                const int cell = ni * 16 + l15;
                Csb[ch * CS_LD + cell] = bf16rne(acc[mi][ni][reg] + bv[mi * 4 + reg]);
            }
    __syncthreads();

    // ---- loss epilogue, 2-way split: waves 0-2 box/obj/cls[0,40); waves 3-5 cls[40,80) ----
    float part[5] = {0.f, 0.f, 0.f, 0.f, 0.f};
    if (t < 384) {
        const int half = (t >= 192) ? 1 : 0;      // wave-uniform (192 = 3 waves)
        const int unit = t - half * 192;
        const int a = unit >> 6;
        const int c = unit & 63;
        const int cg = cell0 + c;
        if (cg < NCELL) {
            const int chb = a * NCH;
            if (half == 0) {
                const int hh = cg / FDIM;
                const int ww = cg - hh * FDIM;
                float v0 = bf16f(Csb[(chb + 0) * CS_LD + c]);
                float v1 = bf16f(Csb[(chb + 1) * CS_LD + c]);
                float v2 = bf16f(Csb[(chb + 2) * CS_LD + c]);
                float v3 = bf16f(Csb[(chb + 3) * CS_LD + c]);
                float v4 = bf16f(Csb[(chb + 4) * CS_LD + c]);
                const float manw[3] = {1.25f, 2.0f, 4.125f};
                const float manh[3] = {1.625f, 3.75f, 2.875f};
                float s0 = sigmf_(v0), s1 = sigmf_(v1), s4 = sigmf_(v4);
                float pw = __expf(v2) * manw[a];
                float ph = __expf(v3) * manh[a];
                float px = s0 + (float)ww, py = s1 + (float)hh;
                float parea = pw * ph;
                float ptlx = px - 0.5f * pw, ptly = py - 0.5f * ph;
                float pbrx = px + 0.5f * pw, pbry = py + 0.5f * ph;

                float maxiou = -1e30f;
                int aidx = -1;
                for (int k = 0; k < KLAB; k++) {
                    const float* r = &Lb[k * 16];
                    float tlx = fmaxf(ptlx, r[0]), tly = fmaxf(ptly, r[1]);
                    float brx = fminf(pbrx, r[2]), bry = fminf(pbry, r[3]);
                    float inter = ((tlx < brx) && (tly < bry)) ? (brx - tlx) * (bry - tly) : 0.0f;
                    float iou = (r[5] != 0.0f) ? inter / (parea + r[4] - inter) : 0.0f;
                    maxiou = fmaxf(maxiou, iou);
                    if (r[12] != 0.0f && (int)r[13] == a && (int)r[14] == ww && (int)r[15] == hh)
                        aidx = k;         // last match wins
                }
                if (aidx >= 0) {
                    const float* r = &Lb[aidx * 16];
                    float sc = r[11], sc2 = sc * sc;
                    part[0] += sc2 * (bce_fullf(s0, r[6]) + bce_fullf(s1, r[7]));
                    float dw = v2 - r[8], dh = v3 - r[9];
                    float whq = dw * dw + dh * dh;
                    part[1] += 0.5f * sc2 * whq;
                    part[2] += bce1f(s4);
                    int ci = (int)r[10];
                    float l2 = (s0 - r[6]) * (s0 - r[6]) + (s1 - r[7]) * (s1 - r[7]) +
                               sc2 * whq + (s4 - 1.0f) * (s4 - 1.0f);
                    float lcls = 0.0f;
                    for (int cc = 0; cc < 40; cc++) {
                        float s = sigmf_(bf16f(Csb[(chb + 5 + cc) * CS_LD + c]));
                        if (cc == ci) { lcls += bce1f(s); l2 += (s - 1.0f) * (s - 1.0f); }
                        else          { lcls += bce0f(s); l2 += s * s; }
                    }
                    part[3] += lcls;
                    part[4] += l2;
                } else {
                    bool objm = !(maxiou > 0.7f);
                    if (objm) { part[2] += bce0f(s4); part[4] += s4 * s4; }
                }
            } else {
                const int hh = cg / FDIM;
                const int ww = cg - hh * FDIM;
                int aidx = -1;
                for (int k = 0; k < KLAB; k++) {
                    const float* r = &Lb[k * 16];
                    if (r[12] != 0.0f && (int)r[13] == a && (int)r[14] == ww && (int)r[15] == hh)
                        aidx = k;         // last match wins
                }
                if (aidx >= 0) {
                    const float* r = &Lb[aidx * 16];
                    int ci = (int)r[10];
                    float lcls = 0.0f, l2 = 0.0f;
                    for (int cc = 40; cc < 80; cc++) {
                        float s = sigmf_(bf16f(Csb[(chb + 5 + cc) * CS_LD + c]));
                        if (cc == ci) { lcls += bce1f(s); l2 += (s - 1.0f) * (s - 1.0f); }
                        else          { lcls += bce0f(s); l2 += s * s; }
                    }
                    part[3] += lcls;
                    part[4] += l2;
                }
            }
        }
    }

#pragma unroll
    for (int i = 0; i < 5; i++) {
        float v = part[i];
        for (int off = 32; off > 0; off >>= 1) v += __shfl_down(v, off);
        if ((t & 63) == 0) red[t >> 6][i] = v;
    }
    __syncthreads();
    if (t == 0) {
        float s[5];
#pragma unroll
        for (int i = 0; i < 5; i++) {
            s[i] = red[0][i];
#pragma unroll
            for (int wv = 1; wv < 8; wv++) s[i] += red[wv][i];
            partials[blk * 8 + i] = s[i];
        }
    }
}

// ---- final reduction over per-block partials ----
__global__ __launch_bounds__(256) void yolo_fin(const float* __restrict__ partials,
                                                float* __restrict__ out) {
    __shared__ float red[4][8];
    const int t = threadIdx.x;
    float s[5] = {0.f, 0.f, 0.f, 0.f, 0.f};
    for (int r = t; r < NBLK; r += 256)
#pragma unroll
        for (int i = 0; i < 5; i++) s[i] += partials[r * 8 + i];
#pragma unroll
    for (int i = 0; i < 5; i++) {
        float v = s[i];
        for (int off = 32; off > 0; off >>= 1) v += __shfl_down(v, off);
        if ((t & 63) == 0) red[t >> 6][i] = v;
    }
    __syncthreads();
    if (t == 0) {
        float xy  = red[0][0] + red[1][0] + red[2][0] + red[3][0];
        float wh  = red[0][1] + red[1][1] + red[2][1] + red[3][1];
        float obj = red[0][2] + red[1][2] + red[2][2] + red[3][2];
        float cls = red[0][3] + red[1][3] + red[2][3] + red[3][3];
        float l2  = red[0][4] + red[1][4] + red[2][4] + red[3][4];
        out[0] = xy + wh + obj + cls;
        out[1] = xy; out[2] = wh; out[3] = obj; out[4] = cls; out[5] = l2;
    }
}

extern "C" void kernel_launch(void* const* d_in, const int* in_sizes, int n_in,
                              void* d_out, int out_size, void* d_ws, size_t ws_size,
                              hipStream_t stream) {
    const float* xin    = (const float*)d_in[0];
    const float* labels = (const float*)d_in[1];
    const float* Wm     = (const float*)d_in[2];
    const float* bias   = (const float*)d_in[3];
    float* out = (float*)d_out;

    float* partials = (float*)d_ws;                            // 46592 B
    float* lrec  = (float*)((char*)d_ws + 46592);              // 40960 B
    u16*   Wbf   = (u16*)((char*)d_ws + 46592 + 40960);        // 131072 B

    yolo_wconv<<<256, 256, 0, stream>>>(Wm, Wbf);
    yolo_lab<<<(NB * KLAB + 63) / 64, 64, 0, stream>>>(labels, lrec);
    yolo_mfma<<<NBLK, 512, 0, stream>>>(xin, Wbf, bias, lrec, partials);
    yolo_fin<<<1, 256, 0, stream>>>(partials, out);
}

// Round 8
// 86.381 us; speedup vs baseline: 1.2249x; 1.2249x over previous
//
#include <hip/hip_runtime.h>
#include <math.h>

typedef unsigned int u32;
typedef unsigned short u16;
typedef __attribute__((ext_vector_type(2))) u32 u32x2;
typedef __attribute__((ext_vector_type(4))) u32 u32x4;
typedef __attribute__((ext_vector_type(8))) short bf16x8;
typedef __attribute__((ext_vector_type(4))) float f32x4;

#define FDIM 76
#define NCELL 5776
#define NA 3
#define NCH 85
#define NCLS 80
#define KLAB 40
#define NB 16
#define CIN 256
#define TILES_PER_B 91
#define NBLK (NB * TILES_PER_B)   // 1456
#define CS_LD 68                  // Csb row stride in u16

// fast-math helpers (epilogue; tolerance is 2% of 2.4e5)
__device__ __forceinline__ float sigmf_(float x) { return __frcp_rn(1.0f + __expf(-x)); }
__device__ __forceinline__ float bce_fullf(float p, float t) {
    return -(t * fmaxf(__logf(p), -100.0f) + (1.0f - t) * fmaxf(__logf(1.0f - p), -100.0f));
}
__device__ __forceinline__ float bce1f(float p) { return -fmaxf(__logf(p), -100.0f); }
__device__ __forceinline__ float bce0f(float p) { return -fmaxf(__logf(1.0f - p), -100.0f); }

__device__ __forceinline__ u16 bf16rne(float f) {
    u32 u = __float_as_uint(f);
    u32 r = u + 0x7fffu + ((u >> 16) & 1u);
    return (u16)(r >> 16);
}
__device__ __forceinline__ float bf16f(u16 v) { return __uint_as_float(((u32)v) << 16); }

// ---- W fp32 -> bf16, padded to [256][256] (row 255 zero) ----
__global__ __launch_bounds__(256) void yolo_wconv(const float* __restrict__ W,
                                                  u16* __restrict__ Wbf) {
    int idx = blockIdx.x * 256 + threadIdx.x;
    int row = idx >> 8, col = idx & 255;
    float v = (row < NA * NCH) ? W[row * CIN + col] : 0.0f;
    Wbf[idx] = bf16rne(v);
}

// ---- label prep (same math as verified r1; repacked float4-aligned + match key) ----
// layout[16]: 0 ttlx 1 ttly 2 tbrx 3 tbry | 4 area 5 valid 6 key 7 scale |
//             8 tvx 9 tvy 10 tlw 11 tlh | 12 cls 13-15 pad
__global__ __launch_bounds__(64) void yolo_lab(const float* __restrict__ labels,
                                               float* __restrict__ lrec) {
    int idx = blockIdx.x * 64 + threadIdx.x;
    if (idx >= NB * KLAB) return;
    const float* l = labels + idx * 5;
    float cls = l[0], x = l[1], y = l[2], ww = l[3], hh = l[4];
    bool valid = (cls + x + y + ww + hh) > 0.0f;
    float tx = x * FDIM, ty = y * FDIM, tw = ww * FDIM, th = hh * FDIM;
    int ti = (int)tx, tj = (int)ty;
    float area_a = (tw - tx) * (th - ty);
    const float aw[9] = {1.25f, 2.0f, 4.125f, 3.75f, 7.75f, 7.375f, 14.5f, 19.5f, 46.625f};
    const float ah[9] = {1.625f, 3.75f, 2.875f, 7.625f, 5.625f, 14.875f, 11.25f, 24.75f, 40.75f};
    float best = -1e30f;
    int bi = 0;
    for (int n = 0; n < 9; n++) {
        float bw = fminf(tw, aw[n]), bh = fminf(th, ah[n]);
        float ai = ((tx < bw) && (ty < bh)) ? (bw - tx) * (bh - ty) : 0.0f;
        float iou = valid ? ai / (area_a + aw[n] * ah[n] - ai) : -1.0f;
        if (iou > best) { best = iou; bi = n; }
    }
    int bn = bi % 3;
    bool assign = valid && (bi < 3);
    float* r = lrec + idx * 16;
    r[0] = tx - 0.5f * tw; r[1] = ty - 0.5f * th;
    r[2] = tx + 0.5f * tw; r[3] = ty + 0.5f * th;
    r[4] = tw * th;
    r[5] = valid ? 1.0f : 0.0f;
    r[6] = assign ? (float)((bn * FDIM + tj) * FDIM + ti) : -1.0f;   // match key
    r[7] = sqrtf(2.0f - tw * th / (float)(FDIM * FDIM));
    r[8] = tx - (float)ti; r[9] = ty - (float)tj;
    r[10] = logf(tw / aw[bn] + 1e-16f); r[11] = logf(th / ah[bn] + 1e-16f);
    r[12] = cls; r[13] = 0.0f; r[14] = 0.0f; r[15] = 0.0f;
}

// ---- fused GEMM+loss: all X loads hoisted to entry (1 latency exposure/block) ----
__global__ __launch_bounds__(512, 4) void yolo_mfma(const float* __restrict__ xin,
                                                    const u16* __restrict__ Wbf,
                                                    const float* __restrict__ bias,
                                                    const float* __restrict__ lrec,
                                                    float* __restrict__ partials) {
    __shared__ char smem[34816];        // GEMM: Xs buf0 [0,8K) buf1 [8K,16K); epi: Csb [256][68] bf16
    __shared__ float Lb[KLAB * 16];
    __shared__ float red[8][8];

    u16* Csb = (u16*)smem;

    const int blk = blockIdx.x;
    const int b = blk / TILES_PER_B;
    const int tile = blk - b * TILES_PER_B;
    const int cell0 = tile * 64;
    const int t = threadIdx.x;
    const int lane = t & 63;
    const int wid = t >> 6;             // 0..7
    const int g = lane >> 4;
    const int l15 = lane & 15;

    // ---- issue ALL X loads for the whole block upfront (32 dword/thread) ----
    const float* xbase = xin + (size_t)b * CIN * NCELL;
    float xv[32];
    {
        const int cell = t & 63;
        const int cg0 = cell0 + cell;
        const int cg = cg0 < NCELL ? cg0 : NCELL - 1;
        const int kq0 = (t >> 6);            // wave id: ii=0 -> plane group kq0, ii=1 -> kq0+8
#pragma unroll
        for (int kc = 0; kc < 4; kc++)
#pragma unroll
            for (int ii = 0; ii < 2; ii++) {
                const int kq = kq0 + ii * 8;
                const float* xp = xbase + (size_t)(kc * 64 + kq * 4) * NCELL + cg;
                xv[kc * 8 + ii * 4 + 0] = xp[0];
                xv[kc * 8 + ii * 4 + 1] = xp[NCELL];
                xv[kc * 8 + ii * 4 + 2] = xp[2 * NCELL];
                xv[kc * 8 + ii * 4 + 3] = xp[3 * NCELL];
            }
    }

    for (int i = t; i < KLAB * 16; i += 512) Lb[i] = lrec[b * KLAB * 16 + i];

    f32x4 acc[2][4];
#pragma unroll
    for (int mi = 0; mi < 2; mi++)
#pragma unroll
        for (int ni = 0; ni < 4; ni++) acc[mi][ni] = (f32x4){0.f, 0.f, 0.f, 0.f};

    const u16* wrow = Wbf + (wid * 32 + l15) * CIN;   // wave owns channels wid*32..+31

#pragma unroll
    for (int kc = 0; kc < 4; kc++) {
        u16* Xs = (u16*)(smem + ((kc & 1) ? 8192 : 0));
        // s=0 W fragment prefetch (L2-hot)
        bf16x8 af0[2];
#pragma unroll
        for (int mi = 0; mi < 2; mi++)
            af0[mi] = *(const bf16x8*)(wrow + mi * 16 * CIN + kc * 64 + g * 8);
        // convert this chunk's registers + LDS write
#pragma unroll
        for (int ii = 0; ii < 2; ii++) {
            const int u = t + ii * 512;
            const int kq = u >> 6, cell = u & 63;
            u32x2 pv;
            pv.x = (u32)bf16rne(xv[kc * 8 + ii * 4 + 0]) | ((u32)bf16rne(xv[kc * 8 + ii * 4 + 1]) << 16);
            pv.y = (u32)bf16rne(xv[kc * 8 + ii * 4 + 2]) | ((u32)bf16rne(xv[kc * 8 + ii * 4 + 3]) << 16);
            const int byte = (cell * 128 + kq * 8) ^ ((cell & 7) << 4);
            *(u32x2*)((char*)Xs + byte) = pv;
        }
        __syncthreads();                 // single barrier per chunk (dbuf-safe, see r7)
        // s = 0
        bf16x8 bfr[4];
#pragma unroll
        for (int ni = 0; ni < 4; ni++) {
            const int cell = ni * 16 + l15;
            const int byte = (cell * 128 + g * 16) ^ ((cell & 7) << 4);
            bfr[ni] = *(const bf16x8*)((char*)Xs + byte);
        }
        bf16x8 af1[2];
#pragma unroll
        for (int mi = 0; mi < 2; mi++)
            af1[mi] = *(const bf16x8*)(wrow + mi * 16 * CIN + kc * 64 + 32 + g * 8);
#pragma unroll
        for (int mi = 0; mi < 2; mi++)
#pragma unroll
            for (int ni = 0; ni < 4; ni++)
                acc[mi][ni] = __builtin_amdgcn_mfma_f32_16x16x32_bf16(
                    af0[mi], bfr[ni], acc[mi][ni], 0, 0, 0);
        // s = 1
#pragma unroll
        for (int ni = 0; ni < 4; ni++) {
            const int cell = ni * 16 + l15;
            const int byte = (cell * 128 + 64 + g * 16) ^ ((cell & 7) << 4);
            bfr[ni] = *(const bf16x8*)((char*)Xs + byte);
        }
#pragma unroll
        for (int mi = 0; mi < 2; mi++)
#pragma unroll
            for (int ni = 0; ni < 4; ni++)
                acc[mi][ni] = __builtin_amdgcn_mfma_f32_16x16x32_bf16(
                    af1[mi], bfr[ni], acc[mi][ni], 0, 0, 0);
    }

    __syncthreads();    // all waves done reading Xs before Csb overwrites the region

    // bias for this thread's 8 output channels
    float bv[8];
#pragma unroll
    for (int mi = 0; mi < 2; mi++)
#pragma unroll
        for (int reg = 0; reg < 4; reg++) {
            const int ch = wid * 32 + mi * 16 + g * 4 + reg;
            bv[mi * 4 + reg] = (ch < NA * NCH) ? bias[ch] : 0.0f;
        }
    // C (+bias) -> LDS bf16 [256][CS_LD]
#pragma unroll
    for (int mi = 0; mi < 2; mi++)
#pragma unroll
        for (int ni = 0; ni < 4; ni++)
#pragma unroll
            for (int reg = 0; reg < 4; reg++) {
                const int ch = wid * 32 + mi * 16 + g * 4 + reg;
                const int cell = ni * 16 + l15;
                Csb[ch * CS_LD + cell] = bf16rne(acc[mi][ni][reg] + bv[mi * 4 + reg]);
            }
    __syncthreads();

    // ---- loss epilogue, 2-way split; b128 label reads + packed-key match ----
    float part[5] = {0.f, 0.f, 0.f, 0.f, 0.f};
    if (t < 384) {
        const int half = (t >= 192) ? 1 : 0;      // wave-uniform (192 = 3 waves)
        const int unit = t - half * 192;
        const int a = unit >> 6;
        const int c = unit & 63;
        const int cg = cell0 + c;
        if (cg < NCELL) {
            const int chb = a * NCH;
            const int hh = cg / FDIM;
            const int ww = cg - hh * FDIM;
            const float mykey = (float)((a * FDIM + hh) * FDIM + ww);
            if (half == 0) {
                float v0 = bf16f(Csb[(chb + 0) * CS_LD + c]);
                float v1 = bf16f(Csb[(chb + 1) * CS_LD + c]);
                float v2 = bf16f(Csb[(chb + 2) * CS_LD + c]);
                float v3 = bf16f(Csb[(chb + 3) * CS_LD + c]);
                float v4 = bf16f(Csb[(chb + 4) * CS_LD + c]);
                const float manw[3] = {1.25f, 2.0f, 4.125f};
                const float manh[3] = {1.625f, 3.75f, 2.875f};
                float s0 = sigmf_(v0), s1 = sigmf_(v1), s4 = sigmf_(v4);
                float pw = __expf(v2) * manw[a];
                float ph = __expf(v3) * manh[a];
                float px = s0 + (float)ww, py = s1 + (float)hh;
                float parea = pw * ph;
                float ptlx = px - 0.5f * pw, ptly = py - 0.5f * ph;
                float pbrx = px + 0.5f * pw, pbry = py + 0.5f * ph;

                float maxiou = -1e30f;
                int aidx = -1;
                for (int k = 0; k < KLAB; k++) {
                    const f32x4 A = *(const f32x4*)&Lb[k * 16];       // ttl/tbr
                    const f32x4 Bq = *(const f32x4*)&Lb[k * 16 + 4];  // area valid key scale
                    float tlx = fmaxf(ptlx, A.x), tly = fmaxf(ptly, A.y);
                    float brx = fminf(pbrx, A.z), bry = fminf(pbry, A.w);
                    float inter = ((tlx < brx) && (tly < bry)) ? (brx - tlx) * (bry - tly) : 0.0f;
                    float iou = (Bq.y != 0.0f) ? inter * __frcp_rn(parea + Bq.x - inter) : 0.0f;
                    maxiou = fmaxf(maxiou, iou);
                    if (Bq.z == mykey) aidx = k;   // last match wins
                }
                if (aidx >= 0) {
                    const f32x4 Bq = *(const f32x4*)&Lb[aidx * 16 + 4];
                    const f32x4 Tv = *(const f32x4*)&Lb[aidx * 16 + 8];
                    float sc = Bq.w, sc2 = sc * sc;
                    part[0] += sc2 * (bce_fullf(s0, Tv.x) + bce_fullf(s1, Tv.y));
                    float dw = v2 - Tv.z, dh = v3 - Tv.w;
                    float whq = dw * dw + dh * dh;
                    part[1] += 0.5f * sc2 * whq;
                    part[2] += bce1f(s4);
                    int ci = (int)Lb[aidx * 16 + 12];
                    float l2 = (s0 - Tv.x) * (s0 - Tv.x) + (s1 - Tv.y) * (s1 - Tv.y) +
                               sc2 * whq + (s4 - 1.0f) * (s4 - 1.0f);
                    float lcls = 0.0f;
                    for (int cc = 0; cc < 40; cc++) {
                        float s = sigmf_(bf16f(Csb[(chb + 5 + cc) * CS_LD + c]));
                        if (cc == ci) { lcls += bce1f(s); l2 += (s - 1.0f) * (s - 1.0f); }
                        else          { lcls += bce0f(s); l2 += s * s; }
                    }
                    part[3] += lcls;
                    part[4] += l2;
                } else {
                    bool objm = !(maxiou > 0.7f);
                    if (objm) { part[2] += bce0f(s4); part[4] += s4 * s4; }
                }
            } else {
                int aidx = -1;
                for (int k = 0; k < KLAB; k++) {
                    const f32x4 Bq = *(const f32x4*)&Lb[k * 16 + 4];
                    if (Bq.z == mykey) aidx = k;   // last match wins
                }
                if (aidx >= 0) {
                    int ci = (int)Lb[aidx * 16 + 12];
                    float lcls = 0.0f, l2 = 0.0f;
                    for (int cc = 40; cc < 80; cc++) {
                        float s = sigmf_(bf16f(Csb[(chb + 5 + cc) * CS_LD + c]));
                        if (cc == ci) { lcls += bce1f(s); l2 += (s - 1.0f) * (s - 1.0f); }
                        else          { lcls += bce0f(s); l2 += s * s; }
                    }
                    part[3] += lcls;
                    part[4] += l2;
                }
            }
        }
    }

#pragma unroll
    for (int i = 0; i < 5; i++) {
        float v = part[i];
        for (int off = 32; off > 0; off >>= 1) v += __shfl_down(v, off);
        if ((t & 63) == 0) red[t >> 6][i] = v;
    }
    __syncthreads();
    if (t == 0) {
        float s[5];
#pragma unroll
        for (int i = 0; i < 5; i++) {
            s[i] = red[0][i];
#pragma unroll
            for (int wv = 1; wv < 8; wv++) s[i] += red[wv][i];
            partials[blk * 8 + i] = s[i];
        }
    }
}

// ---- final reduction over per-block partials ----
__global__ __launch_bounds__(256) void yolo_fin(const float* __restrict__ partials,
                                                float* __restrict__ out) {
    __shared__ float red[4][8];
    const int t = threadIdx.x;
    float s[5] = {0.f, 0.f, 0.f, 0.f, 0.f};
    for (int r = t; r < NBLK; r += 256)
#pragma unroll
        for (int i = 0; i < 5; i++) s[i] += partials[r * 8 + i];
#pragma unroll
    for (int i = 0; i < 5; i++) {
        float v = s[i];
        for (int off = 32; off > 0; off >>= 1) v += __shfl_down(v, off);
        if ((t & 63) == 0) red[t >> 6][i] = v;
    }
    __syncthreads();
    if (t == 0) {
        float xy  = red[0][0] + red[1][0] + red[2][0] + red[3][0];
        float wh  = red[0][1] + red[1][1] + red[2][1] + red[3][1];
        float obj = red[0][2] + red[1][2] + red[2][2] + red[3][2];
        float cls = red[0][3] + red[1][3] + red[2][3] + red[3][3];
        float l2  = red[0][4] + red[1][4] + red[2][4] + red[3][4];
        out[0] = xy + wh + obj + cls;
        out[1] = xy; out[2] = wh; out[3] = obj; out[4] = cls; out[5] = l2;
    }
}

extern "C" void kernel_launch(void* const* d_in, const int* in_sizes, int n_in,
                              void* d_out, int out_size, void* d_ws, size_t ws_size,
                              hipStream_t stream) {
    const float* xin    = (const float*)d_in[0];
    const float* labels = (const float*)d_in[1];
    const float* Wm     = (const float*)d_in[2];
    const float* bias   = (const float*)d_in[3];
    float* out = (float*)d_out;

    float* partials = (float*)d_ws;                            // 46592 B
    float* lrec  = (float*)((char*)d_ws + 46592);              // 40960 B
    u16*   Wbf   = (u16*)((char*)d_ws + 46592 + 40960);        // 131072 B

    yolo_wconv<<<256, 256, 0, stream>>>(Wm, Wbf);
    yolo_lab<<<(NB * KLAB + 63) / 64, 64, 0, stream>>>(labels, lrec);
    yolo_mfma<<<NBLK, 512, 0, stream>>>(xin, Wbf, bias, lrec, partials);
    yolo_fin<<<1, 256, 0, stream>>>(partials, out);
}